// Round 1
// baseline (324.377 us; speedup 1.0000x reference)
//
#include <hip/hip_runtime.h>

// Bidirectional linear RNN (units=1, no bias, linear activation).
//   fw_t = k*x_t + r*fw_{t-1}   (fw_0 = k*x_0)
//   bw_t = k*x_t + r*bw_{t+1}   (bw_{T-1} = k*x_{T-1})
// out0[b,t,:] = (fw, bw); out1 (diff) = zeros.
// One block per row; 256 threads x 16-element segments; cross-thread
// (a,b)-pair scan in LDS (a = r^16 per segment).

constexpr int T_LEN = 4096;
constexpr int SEG   = 16;
constexpr int NT    = 256;   // threads per block = T_LEN / SEG

__global__ __launch_bounds__(NT) void bidir_rnn(
    const float* __restrict__ x,     // [B, T]
    const float* __restrict__ kp,    // [1]
    const float* __restrict__ rp,    // [1]
    float*       __restrict__ out,   // [B, T, 2]
    float*       __restrict__ diff)  // [B, T, 2] -> zeros
{
    const int b   = blockIdx.x;
    const int tid = threadIdx.x;
    const float k = *kp;
    const float r = *rp;

    // pw[i] = r^i, i = 0..16
    float pw[SEG + 1];
    pw[0] = 1.0f;
    #pragma unroll
    for (int i = 1; i <= SEG; ++i) pw[i] = pw[i - 1] * r;

    const size_t rowbase = (size_t)b * T_LEN;

    // ---- load 16 contiguous floats (4x float4) ----
    const float4* xin = (const float4*)(x + rowbase + (size_t)tid * SEG);
    float4 v0 = xin[0], v1 = xin[1], v2 = xin[2], v3 = xin[3];
    float u[SEG] = {v0.x, v0.y, v0.z, v0.w, v1.x, v1.y, v1.z, v1.w,
                    v2.x, v2.y, v2.z, v2.w, v3.x, v3.y, v3.z, v3.w};
    #pragma unroll
    for (int j = 0; j < SEG; ++j) u[j] *= k;

    // ---- local scans (registers) ----
    float lf[SEG], lb[SEG];
    lf[0] = u[0];
    #pragma unroll
    for (int j = 1; j < SEG; ++j) lf[j] = fmaf(r, lf[j - 1], u[j]);
    lb[SEG - 1] = u[SEG - 1];
    #pragma unroll
    for (int j = SEG - 2; j >= 0; --j) lb[j] = fmaf(r, lb[j + 1], u[j]);

    __shared__ float sA[NT], sB[NT];

    // ---- forward cross-thread inclusive scan of (a, b) pairs ----
    sA[tid] = pw[SEG];
    sB[tid] = lf[SEG - 1];
    __syncthreads();
    #pragma unroll
    for (int off = 1; off < NT; off <<= 1) {
        float a_cur = sA[tid], b_cur = sB[tid];
        float a_pre = 0.0f, b_pre = 0.0f;
        if (tid >= off) { a_pre = sA[tid - off]; b_pre = sB[tid - off]; }
        __syncthreads();
        if (tid >= off) {
            sA[tid] = a_pre * a_cur;
            sB[tid] = fmaf(a_cur, b_pre, b_cur);
        }
        __syncthreads();
    }
    const float Hf = (tid == 0) ? 0.0f : sB[tid - 1];  // h at end of prev segment
    __syncthreads();  // before LDS reuse

    // ---- backward scan: same machinery, thread order reversed ----
    const int rt = (NT - 1) - tid;
    sA[rt] = pw[SEG];
    sB[rt] = lb[0];
    __syncthreads();
    #pragma unroll
    for (int off = 1; off < NT; off <<= 1) {
        float a_cur = sA[tid], b_cur = sB[tid];
        float a_pre = 0.0f, b_pre = 0.0f;
        if (tid >= off) { a_pre = sA[tid - off]; b_pre = sB[tid - off]; }
        __syncthreads();
        if (tid >= off) {
            sA[tid] = a_pre * a_cur;
            sB[tid] = fmaf(a_cur, b_pre, b_cur);
        }
        __syncthreads();
    }
    const float Hb = (rt == 0) ? 0.0f : sB[rt - 1];    // bw carry from later segments

    // ---- finalize + store interleaved (fw, bw) pairs ----
    float fw[SEG], bw[SEG];
    #pragma unroll
    for (int j = 0; j < SEG; ++j) {
        fw[j] = fmaf(pw[j + 1],   Hf, lf[j]);
        bw[j] = fmaf(pw[SEG - j], Hb, lb[j]);
    }

    float4* o = (float4*)(out + (rowbase + (size_t)tid * SEG) * 2);
    #pragma unroll
    for (int m = 0; m < 8; ++m) {
        o[m] = make_float4(fw[2 * m], bw[2 * m], fw[2 * m + 1], bw[2 * m + 1]);
    }

    // ---- zero this row of diff (T*2 floats = 2048 float4), coalesced ----
    float4* d = (float4*)(diff + rowbase * 2) + tid;
    const float4 z = make_float4(0.0f, 0.0f, 0.0f, 0.0f);
    #pragma unroll
    for (int m = 0; m < 8; ++m) d[m * NT] = z;
}

extern "C" void kernel_launch(void* const* d_in, const int* in_sizes, int n_in,
                              void* d_out, int out_size, void* d_ws, size_t ws_size,
                              hipStream_t stream) {
    const float* x  = (const float*)d_in[0];
    const float* kp = (const float*)d_in[1];
    const float* rp = (const float*)d_in[2];
    float* out = (float*)d_out;

    const int B = in_sizes[0] / T_LEN;               // 4096
    float* diff = out + (size_t)B * T_LEN * 2;       // second tuple output

    bidir_rnn<<<dim3(B), dim3(NT), 0, stream>>>(x, kp, rp, out, diff);
}

// Round 2
// 318.953 us; speedup vs baseline: 1.0170x; 1.0170x over previous
//
#include <hip/hip_runtime.h>

// Bidirectional linear RNN (units=1, no bias, linear activation).
//   fw_t = k*x_t + r*fw_{t-1};  bw_t = k*x_t + r*bw_{t+1}
// out0[b,t,:] = (fw, bw); out1 (diff) = zeros.
// R2: shuffle-based wave scans (1 barrier for cross-wave combine) + LDS-staged
// coalesced float4 output stores (pad 8->9 float4 layout: <=8-way conflicts,
// ~free vs HBM).

constexpr int T_LEN  = 4096;
constexpr int SEG    = 16;
constexpr int NT     = 256;            // threads per block = T_LEN / SEG
constexpr int NW     = NT / 64;        // 4 waves
constexpr int ROW_F4 = T_LEN * 2 / 4;  // 2048 float4 per output row
constexpr int LDS_F4 = (ROW_F4 / 8) * 9;  // 2304 (pad every 8 float4 with 1)

__global__ __launch_bounds__(NT) void bidir_rnn(
    const float* __restrict__ x,     // [B, T]
    const float* __restrict__ kp,    // [1]
    const float* __restrict__ rp,    // [1]
    float*       __restrict__ out,   // [B, T, 2]
    float*       __restrict__ diff)  // [B, T, 2] -> zeros
{
    const int b    = blockIdx.x;
    const int tid  = threadIdx.x;
    const int lane = tid & 63;
    const int wv   = tid >> 6;
    const float k = *kp;
    const float r = *rp;

    float pw[SEG + 1];
    pw[0] = 1.0f;
    #pragma unroll
    for (int i = 1; i <= SEG; ++i) pw[i] = pw[i - 1] * r;
    const float a16 = pw[SEG];

    const size_t rowbase = (size_t)b * T_LEN;

    // ---- load 16 contiguous floats (4x float4, per-thread contiguous) ----
    const float4* xin = (const float4*)(x + rowbase) + tid * 4;
    float4 v0 = xin[0], v1 = xin[1], v2 = xin[2], v3 = xin[3];
    float u[SEG] = {v0.x, v0.y, v0.z, v0.w, v1.x, v1.y, v1.z, v1.w,
                    v2.x, v2.y, v2.z, v2.w, v3.x, v3.y, v3.z, v3.w};
    #pragma unroll
    for (int j = 0; j < SEG; ++j) u[j] *= k;

    // ---- local scans (registers) ----
    float lf[SEG], lb[SEG];
    lf[0] = u[0];
    #pragma unroll
    for (int j = 1; j < SEG; ++j) lf[j] = fmaf(r, lf[j - 1], u[j]);
    lb[SEG - 1] = u[SEG - 1];
    #pragma unroll
    for (int j = SEG - 2; j >= 0; --j) lb[j] = fmaf(r, lb[j + 1], u[j]);

    // ---- forward wave-inclusive (a,b) scan via shfl_up (time = lane asc) ----
    float af = a16, bf = lf[SEG - 1];
    #pragma unroll
    for (int off = 1; off < 64; off <<= 1) {
        float ap = __shfl_up(af, off);
        float bp = __shfl_up(bf, off);
        if (lane >= off) { bf = fmaf(af, bp, bf); af *= ap; }
    }
    float aef = __shfl_up(af, 1), bef = __shfl_up(bf, 1);   // lane-exclusive
    if (lane == 0) { aef = 1.0f; bef = 0.0f; }

    // ---- backward wave-inclusive scan via shfl_down (time = lane desc) ----
    float ab = a16, bb = lb[0];
    #pragma unroll
    for (int off = 1; off < 64; off <<= 1) {
        float ap = __shfl_down(ab, off);
        float bp = __shfl_down(bb, off);
        if (lane < 64 - off) { bb = fmaf(ab, bp, bb); ab *= ap; }
    }
    float aeb = __shfl_down(ab, 1), beb = __shfl_down(bb, 1);
    if (lane == 63) { aeb = 1.0f; beb = 0.0f; }

    // ---- cross-wave combine (single barrier) ----
    __shared__ float4 sOut[LDS_F4];
    __shared__ float sWa[NW], sWb[NW], sVa[NW], sVb[NW];
    if (lane == 63) { sWa[wv] = af; sWb[wv] = bf; }   // fw wave totals
    if (lane == 0)  { sVa[wv] = ab; sVb[wv] = bb; }   // bw wave totals
    __syncthreads();

    float Pb = 0.0f;                       // fw prefix over earlier waves
    #pragma unroll
    for (int w = 0; w < NW - 1; ++w) {
        if (w < wv) { Pb = fmaf(sWa[w], Pb, sWb[w]); }
    }
    const float Hf = fmaf(aef, Pb, bef);   // h at end of previous segment

    float Qb = 0.0f;                       // bw prefix over later waves
    #pragma unroll
    for (int w = NW - 1; w > 0; --w) {
        if (w > wv) { Qb = fmaf(sVa[w], Qb, sVb[w]); }
    }
    const float Hb = fmaf(aeb, Qb, beb);   // bw h at start of next segment

    // ---- finalize into LDS (padded float4 layout), then coalesced store ----
    #pragma unroll
    for (int q = 0; q < 8; ++q) {
        const int j0 = 2 * q, j1 = 2 * q + 1;
        float4 o;
        o.x = fmaf(pw[j0 + 1],   Hf, lf[j0]);
        o.y = fmaf(pw[SEG - j0], Hb, lb[j0]);
        o.z = fmaf(pw[j1 + 1],   Hf, lf[j1]);
        o.w = fmaf(pw[SEG - j1], Hb, lb[j1]);
        sOut[tid * 9 + q] = o;             // flat f4 idx t*8+q -> (f4>>3)*9+(f4&7)
    }
    __syncthreads();

    float4* orow = (float4*)(out + rowbase * 2);
    #pragma unroll
    for (int q2 = 0; q2 < 8; ++q2) {
        const int f4 = q2 * NT + tid;
        orow[f4] = sOut[(f4 >> 3) * 9 + (f4 & 7)];   // coalesced 1KB/wave store
    }

    // ---- zero this row of diff, coalesced ----
    float4* d = (float4*)(diff + rowbase * 2) + tid;
    const float4 z = make_float4(0.0f, 0.0f, 0.0f, 0.0f);
    #pragma unroll
    for (int m = 0; m < 8; ++m) d[m * NT] = z;
}

extern "C" void kernel_launch(void* const* d_in, const int* in_sizes, int n_in,
                              void* d_out, int out_size, void* d_ws, size_t ws_size,
                              hipStream_t stream) {
    const float* x  = (const float*)d_in[0];
    const float* kp = (const float*)d_in[1];
    const float* rp = (const float*)d_in[2];
    float* out = (float*)d_out;

    const int B = in_sizes[0] / T_LEN;               // 4096
    float* diff = out + (size_t)B * T_LEN * 2;       // second tuple output

    bidir_rnn<<<dim3(B), dim3(NT), 0, stream>>>(x, kp, rp, out, diff);
}

// Round 3
// 315.539 us; speedup vs baseline: 1.0280x; 1.0108x over previous
//
#include <hip/hip_runtime.h>

// Bidirectional linear RNN (units=1, no bias, linear activation).
//   fw_t = k*x_t + r*fw_{t-1};  bw_t = k*x_t + r*bw_{t+1}
// out0[b,t,:] = (fw, bw); out1 (diff) = zeros.
// R3: lean kernel — no LDS output staging (R2 proved store pattern is not the
// bottleneck), shuffle wave scans + 1 barrier, diff zeroed via hipMemsetAsync
// node (fill kernel streams at measured 6.33 TB/s). Max occupancy for latency
// hiding: LDS ~64 B, lb aliased onto u to cut VGPRs.

constexpr int T_LEN = 4096;
constexpr int SEG   = 16;
constexpr int NT    = 256;   // threads per block = T_LEN / SEG
constexpr int NW    = NT / 64;

__global__ __launch_bounds__(NT) void bidir_rnn(
    const float* __restrict__ x,     // [B, T]
    const float* __restrict__ kp,    // [1]
    const float* __restrict__ rp,    // [1]
    float*       __restrict__ out)   // [B, T, 2]
{
    const int b    = blockIdx.x;
    const int tid  = threadIdx.x;
    const int lane = tid & 63;
    const int wv   = tid >> 6;
    const float k = *kp;
    const float r = *rp;

    float pw[SEG + 1];
    pw[0] = 1.0f;
    #pragma unroll
    for (int i = 1; i <= SEG; ++i) pw[i] = pw[i - 1] * r;
    const float a16 = pw[SEG];

    const size_t rowbase = (size_t)b * T_LEN;

    // ---- load 16 contiguous floats (4x float4, per-thread contiguous) ----
    const float4* xin = (const float4*)(x + rowbase) + tid * 4;
    float4 v0 = xin[0], v1 = xin[1], v2 = xin[2], v3 = xin[3];
    float u[SEG] = {v0.x, v0.y, v0.z, v0.w, v1.x, v1.y, v1.z, v1.w,
                    v2.x, v2.y, v2.z, v2.w, v3.x, v3.y, v3.z, v3.w};
    #pragma unroll
    for (int j = 0; j < SEG; ++j) u[j] *= k;

    // ---- local scans: lf forward; backward scan IN PLACE into u (-> lb) ----
    float lf[SEG];
    lf[0] = u[0];
    #pragma unroll
    for (int j = 1; j < SEG; ++j) lf[j] = fmaf(r, lf[j - 1], u[j]);
    #pragma unroll
    for (int j = SEG - 2; j >= 0; --j) u[j] = fmaf(r, u[j + 1], u[j]);
    // u[j] now holds lb[j] (local backward suffix scan)

    // ---- forward wave-inclusive (a,b) scan via shfl_up (time = lane asc) ----
    float af = a16, bf = lf[SEG - 1];
    #pragma unroll
    for (int off = 1; off < 64; off <<= 1) {
        float ap = __shfl_up(af, off);
        float bp = __shfl_up(bf, off);
        if (lane >= off) { bf = fmaf(af, bp, bf); af *= ap; }
    }
    float aef = __shfl_up(af, 1), bef = __shfl_up(bf, 1);   // lane-exclusive
    if (lane == 0) { aef = 1.0f; bef = 0.0f; }

    // ---- backward wave-inclusive scan via shfl_down (time = lane desc) ----
    float ab = a16, bb = u[0];
    #pragma unroll
    for (int off = 1; off < 64; off <<= 1) {
        float ap = __shfl_down(ab, off);
        float bp = __shfl_down(bb, off);
        if (lane < 64 - off) { bb = fmaf(ab, bp, bb); ab *= ap; }
    }
    float aeb = __shfl_down(ab, 1), beb = __shfl_down(bb, 1);
    if (lane == 63) { aeb = 1.0f; beb = 0.0f; }

    // ---- cross-wave combine (single barrier, tiny LDS) ----
    __shared__ float sWa[NW], sWb[NW], sVa[NW], sVb[NW];
    if (lane == 63) { sWa[wv] = af; sWb[wv] = bf; }   // fw wave totals
    if (lane == 0)  { sVa[wv] = ab; sVb[wv] = bb; }   // bw wave totals
    __syncthreads();

    float Pb = 0.0f;                       // fw prefix over earlier waves
    #pragma unroll
    for (int w = 0; w < NW - 1; ++w) {
        if (w < wv) { Pb = fmaf(sWa[w], Pb, sWb[w]); }
    }
    const float Hf = fmaf(aef, Pb, bef);   // fw carry into this segment

    float Qb = 0.0f;                       // bw prefix over later waves
    #pragma unroll
    for (int w = NW - 1; w > 0; --w) {
        if (w > wv) { Qb = fmaf(sVa[w], Qb, sVb[w]); }
    }
    const float Hb = fmaf(aeb, Qb, beb);   // bw carry into this segment

    // ---- finalize + store: per-thread 128 B contiguous (8x float4) ----
    float4* o = (float4*)(out + rowbase * 2) + tid * 8;
    #pragma unroll
    for (int m = 0; m < 8; ++m) {
        const int j0 = 2 * m, j1 = 2 * m + 1;
        float4 v;
        v.x = fmaf(pw[j0 + 1],   Hf, lf[j0]);
        v.y = fmaf(pw[SEG - j0], Hb, u[j0]);
        v.z = fmaf(pw[j1 + 1],   Hf, lf[j1]);
        v.w = fmaf(pw[SEG - j1], Hb, u[j1]);
        o[m] = v;
    }
}

extern "C" void kernel_launch(void* const* d_in, const int* in_sizes, int n_in,
                              void* d_out, int out_size, void* d_ws, size_t ws_size,
                              hipStream_t stream) {
    const float* x  = (const float*)d_in[0];
    const float* kp = (const float*)d_in[1];
    const float* rp = (const float*)d_in[2];
    float* out = (float*)d_out;

    const int B = in_sizes[0] / T_LEN;               // 4096
    float* diff = out + (size_t)B * T_LEN * 2;       // second tuple output

    // diff == 0 everywhere: offload 134 MB of zero-stores to an optimized
    // fill (graph-capturable memset node, ~6.33 TB/s measured).
    hipMemsetAsync(diff, 0, (size_t)B * T_LEN * 2 * sizeof(float), stream);

    bidir_rnn<<<dim3(B), dim3(NT), 0, stream>>>(x, kp, rp, out);
}

// Round 4
// 306.865 us; speedup vs baseline: 1.0571x; 1.0283x over previous
//
#include <hip/hip_runtime.h>

// Bidirectional linear RNN (units=1, no bias, linear activation).
//   fw_t = k*x_t + r*fw_{t-1};  bw_t = k*x_t + r*bw_{t+1}
// out0[b,t,:] = (fw, bw); out1 (diff) = zeros (via memset node).
// R4: R3's lean shuffle-scan + split memset, PLUS R2's LDS-staged coalesced
// output stores (padded 8->9 float4 layout). R2-R1 isolated the store-instr
// request-rate cost (-5.4us); R3-R2 isolated lean-scan+memset (-3.5us); this
// combines both.

constexpr int T_LEN  = 4096;
constexpr int SEG    = 16;
constexpr int NT     = 256;            // threads per block = T_LEN / SEG
constexpr int NW     = NT / 64;        // 4 waves
constexpr int ROW_F4 = T_LEN * 2 / 4;  // 2048 float4 per output row
constexpr int LDS_F4 = (ROW_F4 / 8) * 9;  // 2304 (pad every 8 float4 with 1)

__global__ __launch_bounds__(NT) void bidir_rnn(
    const float* __restrict__ x,     // [B, T]
    const float* __restrict__ kp,    // [1]
    const float* __restrict__ rp,    // [1]
    float*       __restrict__ out)   // [B, T, 2]
{
    const int b    = blockIdx.x;
    const int tid  = threadIdx.x;
    const int lane = tid & 63;
    const int wv   = tid >> 6;
    const float k = *kp;
    const float r = *rp;

    float pw[SEG + 1];
    pw[0] = 1.0f;
    #pragma unroll
    for (int i = 1; i <= SEG; ++i) pw[i] = pw[i - 1] * r;
    const float a16 = pw[SEG];

    const size_t rowbase = (size_t)b * T_LEN;

    // ---- load 16 contiguous floats (4x float4, per-thread contiguous) ----
    const float4* xin = (const float4*)(x + rowbase) + tid * 4;
    float4 v0 = xin[0], v1 = xin[1], v2 = xin[2], v3 = xin[3];
    float u[SEG] = {v0.x, v0.y, v0.z, v0.w, v1.x, v1.y, v1.z, v1.w,
                    v2.x, v2.y, v2.z, v2.w, v3.x, v3.y, v3.z, v3.w};
    #pragma unroll
    for (int j = 0; j < SEG; ++j) u[j] *= k;

    // ---- local scans: lf forward; backward scan IN PLACE into u (-> lb) ----
    float lf[SEG];
    lf[0] = u[0];
    #pragma unroll
    for (int j = 1; j < SEG; ++j) lf[j] = fmaf(r, lf[j - 1], u[j]);
    #pragma unroll
    for (int j = SEG - 2; j >= 0; --j) u[j] = fmaf(r, u[j + 1], u[j]);
    // u[j] now holds lb[j]

    // ---- forward wave-inclusive (a,b) scan via shfl_up (time = lane asc) ----
    float af = a16, bf = lf[SEG - 1];
    #pragma unroll
    for (int off = 1; off < 64; off <<= 1) {
        float ap = __shfl_up(af, off);
        float bp = __shfl_up(bf, off);
        if (lane >= off) { bf = fmaf(af, bp, bf); af *= ap; }
    }
    float aef = __shfl_up(af, 1), bef = __shfl_up(bf, 1);   // lane-exclusive
    if (lane == 0) { aef = 1.0f; bef = 0.0f; }

    // ---- backward wave-inclusive scan via shfl_down (time = lane desc) ----
    float ab = a16, bb = u[0];
    #pragma unroll
    for (int off = 1; off < 64; off <<= 1) {
        float ap = __shfl_down(ab, off);
        float bp = __shfl_down(bb, off);
        if (lane < 64 - off) { bb = fmaf(ab, bp, bb); ab *= ap; }
    }
    float aeb = __shfl_down(ab, 1), beb = __shfl_down(bb, 1);
    if (lane == 63) { aeb = 1.0f; beb = 0.0f; }

    // ---- cross-wave combine (single barrier, tiny LDS) ----
    __shared__ float4 sOut[LDS_F4];
    __shared__ float sWa[NW], sWb[NW], sVa[NW], sVb[NW];
    if (lane == 63) { sWa[wv] = af; sWb[wv] = bf; }   // fw wave totals
    if (lane == 0)  { sVa[wv] = ab; sVb[wv] = bb; }   // bw wave totals
    __syncthreads();

    float Pb = 0.0f;                       // fw prefix over earlier waves
    #pragma unroll
    for (int w = 0; w < NW - 1; ++w) {
        if (w < wv) { Pb = fmaf(sWa[w], Pb, sWb[w]); }
    }
    const float Hf = fmaf(aef, Pb, bef);   // fw carry into this segment

    float Qb = 0.0f;                       // bw prefix over later waves
    #pragma unroll
    for (int w = NW - 1; w > 0; --w) {
        if (w > wv) { Qb = fmaf(sVa[w], Qb, sVb[w]); }
    }
    const float Hb = fmaf(aeb, Qb, beb);   // bw carry into this segment

    // ---- finalize into LDS (padded float4 layout) ----
    #pragma unroll
    for (int q = 0; q < 8; ++q) {
        const int j0 = 2 * q, j1 = 2 * q + 1;
        float4 o;
        o.x = fmaf(pw[j0 + 1],   Hf, lf[j0]);
        o.y = fmaf(pw[SEG - j0], Hb, u[j0]);
        o.z = fmaf(pw[j1 + 1],   Hf, lf[j1]);
        o.w = fmaf(pw[SEG - j1], Hb, u[j1]);
        sOut[tid * 9 + q] = o;             // flat f4 idx t*8+q -> (f4>>3)*9+(f4&7)
    }
    __syncthreads();

    // ---- truly coalesced stores: 1 KB/wave per instruction ----
    float4* orow = (float4*)(out + rowbase * 2);
    #pragma unroll
    for (int q2 = 0; q2 < 8; ++q2) {
        const int f4 = q2 * NT + tid;
        orow[f4] = sOut[(f4 >> 3) * 9 + (f4 & 7)];
    }
}

extern "C" void kernel_launch(void* const* d_in, const int* in_sizes, int n_in,
                              void* d_out, int out_size, void* d_ws, size_t ws_size,
                              hipStream_t stream) {
    const float* x  = (const float*)d_in[0];
    const float* kp = (const float*)d_in[1];
    const float* rp = (const float*)d_in[2];
    float* out = (float*)d_out;

    const int B = in_sizes[0] / T_LEN;               // 4096
    float* diff = out + (size_t)B * T_LEN * 2;       // second tuple output

    // diff == 0 everywhere: offload 134 MB of zero-stores to the fill kernel
    // (graph-capturable memset node, measured ~6.6 TB/s).
    hipMemsetAsync(diff, 0, (size_t)B * T_LEN * 2 * sizeof(float), stream);

    bidir_rnn<<<dim3(B), dim3(NT), 0, stream>>>(x, kp, rp, out);
}